// Round 4
// baseline (182.894 us; speedup 1.0000x reference)
//
#include <hip/hip_runtime.h>
#include <hip/hip_bf16.h>

typedef __attribute__((ext_vector_type(8))) short bf16x8;
typedef __attribute__((ext_vector_type(8))) unsigned short u16x8;
typedef __attribute__((ext_vector_type(4))) float f32x4;

#define BM 128
#define NBLK (262144 / BM)   // 2048

// ws layout (bf16 elems, as u16):
//  [0      , 65536) : W1 chunk images: 8 chunks x 8192 elems; chunk kc, elem e: n=e/72, kl=e%72 -> W1[n][kc*64+kl], zero padded
//  [65536  , 73728) : Wtheta [64][128]
//  [73728  , 80896) : piT    [112][64]
#define WS_WT 65536
#define WS_PI 73728
#define PREP_TOT 80896

__device__ __forceinline__ unsigned short bfc(float f) {
    union { float f; unsigned u; } v; v.f = f;
    unsigned r = (v.u + 0x7fffu + ((v.u >> 16) & 1u)) >> 16;   // RNE
    return (unsigned short)r;
}

__device__ __forceinline__ unsigned pack2(float a, float b) {
    float2 t; t.x = a; t.y = b;
    __hip_bfloat162 h2 = __float22bfloat162_rn(t);
    union { __hip_bfloat162 h; unsigned u; } v; v.h = h2;
    return v.u;
}

__device__ __forceinline__ unsigned short bf1(float a) {
    __hip_bfloat16 h = __float2bfloat16(a);
    union { __hip_bfloat16 h; unsigned short u; } v; v.h = h;
    return v.u;
}

// 8 fp32 (two float4, k-contiguous) -> bf16x8 fragment
__device__ __forceinline__ bf16x8 pack8(float4 lo, float4 hi) {
    union { bf16x8 v; unsigned u[4]; } r;
    r.u[0] = pack2(lo.x, lo.y);
    r.u[1] = pack2(lo.z, lo.w);
    r.u[2] = pack2(hi.x, hi.y);
    r.u[3] = pack2(hi.z, hi.w);
    return r.v;
}

__global__ void prep_kernel(const float* __restrict__ W1, const float* __restrict__ Wt,
                            const float* __restrict__ pi, unsigned short* __restrict__ ws) {
    int i = blockIdx.x * 256 + threadIdx.x;
    if (i >= PREP_TOT) return;
    float v = 0.0f;
    if (i < WS_WT) {
        int kc = i >> 13, e = i & 8191;
        int n = e / 72, kl = e - n * 72;
        if (n < 100 && kl < 64) v = W1[n * 512 + (kc << 6) + kl];
    } else if (i < WS_PI) {
        int e = i - WS_WT;
        int n = e >> 7, k = e & 127;
        if (n < 63 && k < 100) v = Wt[n * 100 + k];
    } else {
        int e = i - WS_PI;
        int c = e >> 6, l = e & 63;
        if (c < 100) v = pi[l * 100 + c];
    }
    ws[i] = bfc(v);
}

__global__ __launch_bounds__(256, 3) void treenet_kernel(
    const float* __restrict__ x, const float* __restrict__ b1,
    const float* __restrict__ bth, const unsigned short* __restrict__ ws,
    float* __restrict__ out)
{
    __shared__ __align__(16) unsigned char smem[34816];
    unsigned short* Hl  = (unsigned short*)smem;            // [128][136] bf16 (GEMM2 input)
    float*          Dl  = (float*)smem;                     // [128][65] f32  (aliases Hl)
    unsigned short* Mul = (unsigned short*)smem;            // [128][72] bf16 (aliases Dl)

    const int tid  = threadIdx.x;
    const int lane = tid & 63;
    const int wv   = tid >> 6;                 // wave 0..3 -> rows wv*32..wv*32+31
    const int lm   = lane & 15;                // A-row / B-col component
    const int lk   = (lane >> 4) << 3;         // per-lane k offset (identical map on A and B)
    const int crow = (wv << 5) + ((lane >> 4) << 2);  // C/D row base (m89 layout)
    const int row0 = blockIdx.x * BM;

    // ---------------- GEMM1: H = relu(X @ W1^T + b1), K=512 ----------------
    // No LDS, no barriers: each lane loads its A fragments straight from x
    // (8 contiguous fp32 -> cvt_pk -> bf16x8); B fragments straight from the
    // pre-packed, L2-resident ws image (identical per wave -> L2 broadcast).
    const float* xr0 = x + (size_t)(row0 + (wv << 5) + lm) * 512 + lk;       // af0 rows
    const float* xr1 = xr0 + (size_t)16 * 512;                               // af1 rows
    const unsigned short* wb = ws + lm * 72 + lk;                            // B frag base

    f32x4 acc[2][7] = {};

    #pragma unroll 2
    for (int kc = 0; kc < 8; ++kc) {
        const int kb = kc << 6;   // fp32 offset of this chunk
        // A fragments: rows (wv*32+lm, wv*32+16+lm), k = kb + {0,32} + lk + 0..7
        float4 a0l = *(const float4*)(xr0 + kb);
        float4 a0h = *(const float4*)(xr0 + kb + 4);
        float4 a1l = *(const float4*)(xr0 + kb + 32);
        float4 a1h = *(const float4*)(xr0 + kb + 36);
        float4 c0l = *(const float4*)(xr1 + kb);
        float4 c0h = *(const float4*)(xr1 + kb + 4);
        float4 c1l = *(const float4*)(xr1 + kb + 32);
        float4 c1h = *(const float4*)(xr1 + kb + 36);
        bf16x8 af00 = pack8(a0l, a0h);   // fr=0, ks=0
        bf16x8 af01 = pack8(a1l, a1h);   // fr=0, ks=1
        bf16x8 af10 = pack8(c0l, c0h);   // fr=1, ks=0
        bf16x8 af11 = pack8(c1l, c1h);   // fr=1, ks=1
        const unsigned short* wc = wb + (kc << 13);
        #pragma unroll
        for (int fc = 0; fc < 7; ++fc) {
            bf16x8 b0 = *(const bf16x8*)(wc + fc * (16 * 72));        // ks=0
            bf16x8 b1 = *(const bf16x8*)(wc + fc * (16 * 72) + 32);   // ks=1
            acc[0][fc] = __builtin_amdgcn_mfma_f32_16x16x32_bf16(af00, b0, acc[0][fc], 0, 0, 0);
            acc[1][fc] = __builtin_amdgcn_mfma_f32_16x16x32_bf16(af10, b0, acc[1][fc], 0, 0, 0);
            acc[0][fc] = __builtin_amdgcn_mfma_f32_16x16x32_bf16(af01, b1, acc[0][fc], 0, 0, 0);
            acc[1][fc] = __builtin_amdgcn_mfma_f32_16x16x32_bf16(af11, b1, acc[1][fc], 0, 0, 0);
        }
    }

    // epilogue: bias + relu -> H (bf16) in LDS, K-padded to 128
    #pragma unroll
    for (int fc = 0; fc < 7; ++fc) {
        int c = (fc << 4) + lm;
        float bb = (c < 100) ? b1[c] : 0.0f;
        #pragma unroll
        for (int fr = 0; fr < 2; ++fr)
            #pragma unroll
            for (int r = 0; r < 4; ++r) {
                float h = acc[fr][fc][r] + bb;
                h = h > 0.0f ? h : 0.0f;
                Hl[(crow + (fr << 4) + r) * 136 + c] = bf1(h);
            }
    }
    {   // zero-fill H[:,112..127]
        u16x8 z = {0,0,0,0,0,0,0,0};
        *(u16x8*)(Hl + (tid >> 1) * 136 + 112 + ((tid & 1) << 3)) = z;
    }
    __syncthreads();

    // ---------------- GEMM2: D = sigmoid(H @ Wtheta^T + bth), K=128 ----------------
    f32x4 acc2[2][4] = {};
    const unsigned short* Wt = ws + WS_WT;
    #pragma unroll
    for (int ks = 0; ks < 4; ++ks) {
        const int k0 = (ks << 5) + lk;
        bf16x8 af0 = *(const bf16x8*)(Hl + ((wv << 5) + lm) * 136 + k0);
        bf16x8 af1 = *(const bf16x8*)(Hl + ((wv << 5) + 16 + lm) * 136 + k0);
        #pragma unroll
        for (int fc = 0; fc < 4; ++fc) {
            bf16x8 bf = *(const bf16x8*)(Wt + ((fc << 4) + lm) * 128 + k0);
            acc2[0][fc] = __builtin_amdgcn_mfma_f32_16x16x32_bf16(af0, bf, acc2[0][fc], 0, 0, 0);
            acc2[1][fc] = __builtin_amdgcn_mfma_f32_16x16x32_bf16(af1, bf, acc2[1][fc], 0, 0, 0);
        }
    }
    __syncthreads();   // done reading Hl; Dl aliases it
    #pragma unroll
    for (int fc = 0; fc < 4; ++fc) {
        int c = (fc << 4) + lm;
        float bb = (c < 63) ? bth[c] : 0.0f;
        #pragma unroll
        for (int fr = 0; fr < 2; ++fr)
            #pragma unroll
            for (int r = 0; r < 4; ++r) {
                float t = acc2[fr][fc][r] + bb;
                float d = 1.0f / (1.0f + __expf(-t));
                Dl[(crow + (fr << 4) + r) * 65 + c] = d;
            }
    }
    __syncthreads();

    // ---------------- tree products: mu (2 threads per row, 32 leaves each) ----------------
    {
        const int row = tid >> 1, p = tid & 1;
        const float* Dr = Dl + row * 65;
        float d0 = Dr[0];
        float m1 = p ? (1.0f - d0) : d0;
        float dA = Dr[1 + p];
        float m2[2]; m2[0] = m1 * dA; m2[1] = m1 * (1.0f - dA);
        float m4[4];
        #pragma unroll
        for (int i = 0; i < 2; ++i) { float d = Dr[3 + (p << 1) + i];  m4[2*i] = m2[i]*d;  m4[2*i+1] = m2[i]*(1.0f-d); }
        float m8[8];
        #pragma unroll
        for (int i = 0; i < 4; ++i) { float d = Dr[7 + (p << 2) + i];  m8[2*i] = m4[i]*d;  m8[2*i+1] = m4[i]*(1.0f-d); }
        float m16[16];
        #pragma unroll
        for (int i = 0; i < 8; ++i) { float d = Dr[15 + (p << 3) + i]; m16[2*i] = m8[i]*d; m16[2*i+1] = m8[i]*(1.0f-d); }
        float dleaf[16];
        #pragma unroll
        for (int i = 0; i < 16; ++i) dleaf[i] = Dr[31 + (p << 4) + i];
        __syncthreads();   // all reads of Dl complete; Mul may now alias it
        unsigned short* Mr = Mul + row * 72 + (p << 5);
        #pragma unroll
        for (int i = 0; i < 16; ++i) {
            float a = m16[i] * dleaf[i], b = m16[i] * (1.0f - dleaf[i]);
            *(unsigned*)(Mr + (i << 1)) = pack2(a, b);
        }
    }
    __syncthreads();

    // ---------------- GEMM3: out = mu @ pi, K=64 ----------------
    f32x4 acc3[2][7] = {};
    const unsigned short* piT = ws + WS_PI;
    #pragma unroll
    for (int ks = 0; ks < 2; ++ks) {
        const int k0 = (ks << 5) + lk;
        bf16x8 af0 = *(const bf16x8*)(Mul + ((wv << 5) + lm) * 72 + k0);
        bf16x8 af1 = *(const bf16x8*)(Mul + ((wv << 5) + 16 + lm) * 72 + k0);
        #pragma unroll
        for (int fc = 0; fc < 7; ++fc) {
            bf16x8 bf = *(const bf16x8*)(piT + ((fc << 4) + lm) * 64 + k0);
            acc3[0][fc] = __builtin_amdgcn_mfma_f32_16x16x32_bf16(af0, bf, acc3[0][fc], 0, 0, 0);
            acc3[1][fc] = __builtin_amdgcn_mfma_f32_16x16x32_bf16(af1, bf, acc3[1][fc], 0, 0, 0);
        }
    }
    #pragma unroll
    for (int fc = 0; fc < 7; ++fc) {
        int c = (fc << 4) + lm;
        if (c < 100) {
            #pragma unroll
            for (int fr = 0; fr < 2; ++fr)
                #pragma unroll
                for (int r = 0; r < 4; ++r)
                    out[(size_t)(row0 + crow + (fr << 4) + r) * 100 + c] = acc3[fr][fc][r];
        }
    }
}

extern "C" void kernel_launch(void* const* d_in, const int* in_sizes, int n_in,
                              void* d_out, int out_size, void* d_ws, size_t ws_size,
                              hipStream_t stream) {
    const float* x   = (const float*)d_in[0];
    const float* W1  = (const float*)d_in[1];
    const float* b1  = (const float*)d_in[2];
    const float* Wt  = (const float*)d_in[3];
    const float* bth = (const float*)d_in[4];
    const float* pi  = (const float*)d_in[5];
    unsigned short* ws = (unsigned short*)d_ws;

    prep_kernel<<<(PREP_TOT + 255) / 256, 256, 0, stream>>>(W1, Wt, pi, ws);
    treenet_kernel<<<NBLK, 256, 0, stream>>>(x, b1, bth, ws, (float*)d_out);
}

// Round 5
// 159.176 us; speedup vs baseline: 1.1490x; 1.1490x over previous
//
#include <hip/hip_runtime.h>
#include <hip/hip_bf16.h>

typedef __attribute__((ext_vector_type(8))) short bf16x8;
typedef __attribute__((ext_vector_type(8))) unsigned short u16x8;
typedef __attribute__((ext_vector_type(4))) float f32x4;

#define BM 128
#define NBLK (262144 / BM)   // 2048

// ws layout (bf16 elems, as u16):
//  [0      , 65536) : W1 chunk images: 8 chunks x 8192 elems; chunk kc, elem e: n=e/72, kl=e%72 -> W1[n][kc*64+kl], zero padded
//  [65536  , 73728) : Wtheta [64][128]
//  [73728  , 80896) : piT    [112][64]
#define WS_WT 65536
#define WS_PI 73728
#define PREP_TOT 80896

#define WAIT_LGKM0 asm volatile("s_waitcnt lgkmcnt(0)" ::: "memory")
#define WAIT_VM8   asm volatile("s_waitcnt vmcnt(8)" ::: "memory")
#define WAIT_VM0   asm volatile("s_waitcnt vmcnt(0)" ::: "memory")
#define SBAR do { __builtin_amdgcn_sched_barrier(0); __builtin_amdgcn_s_barrier(); __builtin_amdgcn_sched_barrier(0); } while (0)

__device__ __forceinline__ unsigned short bfc(float f) {
    union { float f; unsigned u; } v; v.f = f;
    unsigned r = (v.u + 0x7fffu + ((v.u >> 16) & 1u)) >> 16;   // RNE
    return (unsigned short)r;
}

__device__ __forceinline__ unsigned pack2(float a, float b) {
    float2 t; t.x = a; t.y = b;
    __hip_bfloat162 h2 = __float22bfloat162_rn(t);
    union { __hip_bfloat162 h; unsigned u; } v; v.h = h2;
    return v.u;
}

__device__ __forceinline__ unsigned short bf1(float a) {
    __hip_bfloat16 h = __float2bfloat16(a);
    union { __hip_bfloat16 h; unsigned short u; } v; v.h = h;
    return v.u;
}

#define GLLDS16(g, l) __builtin_amdgcn_global_load_lds( \
    (const __attribute__((address_space(1))) void*)(g), \
    (__attribute__((address_space(3))) void*)(l), 16, 0, 0)

__global__ void prep_kernel(const float* __restrict__ W1, const float* __restrict__ Wt,
                            const float* __restrict__ pi, unsigned short* __restrict__ ws) {
    int i = blockIdx.x * 256 + threadIdx.x;
    if (i >= PREP_TOT) return;
    float v = 0.0f;
    if (i < WS_WT) {
        int kc = i >> 13, e = i & 8191;
        int n = e / 72, kl = e - n * 72;
        if (n < 100 && kl < 64) v = W1[n * 512 + (kc << 6) + kl];
    } else if (i < WS_PI) {
        int e = i - WS_WT;
        int n = e >> 7, k = e & 127;
        if (n < 63 && k < 100) v = Wt[n * 100 + k];
    } else {
        int e = i - WS_PI;
        int c = e >> 6, l = e & 63;
        if (c < 100) v = pi[l * 100 + c];
    }
    ws[i] = bfc(v);
}

__global__ __launch_bounds__(256, 4) void treenet_kernel(
    const float* __restrict__ x, const float* __restrict__ b1,
    const float* __restrict__ bth, const unsigned short* __restrict__ ws,
    float* __restrict__ out)
{
    __shared__ __align__(16) unsigned char smem[34816];
    unsigned short* Xl  = (unsigned short*)smem;            // [128][72] bf16 (GEMM1)
    unsigned short* W1c = (unsigned short*)(smem + 18432);  // 8192 elems (GEMM1)
    unsigned short* Hl  = (unsigned short*)smem;            // [128][136] bf16 (aliases)
    float*          Dl  = (float*)smem;                     // [128][65] f32  (aliases Hl)
    unsigned short* Mul = (unsigned short*)smem;            // [128][72] bf16 (aliases Dl)

    const int tid  = threadIdx.x;
    const int lane = tid & 63;
    const int wv   = tid >> 6;
    const int lm   = lane & 15;
    const int lk   = (lane >> 4) << 3;
    const int crow = (wv << 5) + ((lane >> 4) << 2);
    const int row0 = blockIdx.x * BM;

    // ---------------- GEMM1: H = relu(X @ W1^T + b1), K=512 in 8 chunks ----------------
    // Dense staging: each thread owns float4-unit u = it*256+tid of the chunk
    // (row = u>>4, col4 = u&15). Consecutive lanes load consecutive 16B ->
    // fully dense 256B segments (vs the old 16B-at-32B-stride half-density).
    const float* xsrc = x + (size_t)row0 * 512;
    float4 XR[8];
    #pragma unroll
    for (int it = 0; it < 8; ++it) {
        int u = it * 256 + tid;
        XR[it] = *(const float4*)(xsrc + (size_t)(u >> 4) * 512 + ((u & 15) << 2));
    }
    f32x4 acc[2][7] = {};

    for (int kc = 0; kc < 8; ++kc) {
        // 1. issue this chunk's W1 image: global(ws, L2) -> LDS direct (vmcnt +4)
        {
            const unsigned short* src = ws + (kc << 13);
            #pragma unroll
            for (int it = 0; it < 4; ++it) {
                int u = it * 256 + tid;
                GLLDS16(src + (u << 3), W1c + (u << 3));
            }
        }
        // 2. stage X regs (cvt_pk) -> LDS, 8B per unit
        #pragma unroll
        for (int it = 0; it < 8; ++it) {
            int u = it * 256 + tid; int r = u >> 4, c4 = (u & 15) << 2;
            uint2 pk;
            pk.x = pack2(XR[it].x, XR[it].y);
            pk.y = pack2(XR[it].z, XR[it].w);
            *(uint2*)(Xl + r * 72 + c4) = pk;
        }
        // 3. issue next chunk's X loads NOW (vmcnt +8) — stay in flight across
        //    both barriers and the MFMA phase (counted vmcnt, never drained)
        if (kc < 7) {
            const float* src = xsrc + ((kc + 1) << 6);
            #pragma unroll
            for (int it = 0; it < 8; ++it) {
                int u = it * 256 + tid;
                XR[it] = *(const float4*)(src + (size_t)(u >> 4) * 512 + ((u & 15) << 2));
            }
            WAIT_LGKM0;           // my ds_writes visible
            WAIT_VM8;             // 4 gllds done; 8 X loads stay in flight
        } else {
            WAIT_LGKM0;
            WAIT_VM0;             // last chunk: drain gllds (no prefetch outstanding)
        }
        SBAR;   // all waves staged
        // 4. MFMA phase
        #pragma unroll
        for (int ks = 0; ks < 2; ++ks) {
            const int k0 = (ks << 5) + lk;
            bf16x8 af0 = *(const bf16x8*)(Xl + ((wv << 5) + lm) * 72 + k0);
            bf16x8 af1 = *(const bf16x8*)(Xl + ((wv << 5) + 16 + lm) * 72 + k0);
            #pragma unroll
            for (int fc = 0; fc < 7; ++fc) {
                bf16x8 bf = *(const bf16x8*)(W1c + ((fc << 4) + lm) * 72 + k0);
                acc[0][fc] = __builtin_amdgcn_mfma_f32_16x16x32_bf16(af0, bf, acc[0][fc], 0, 0, 0);
                acc[1][fc] = __builtin_amdgcn_mfma_f32_16x16x32_bf16(af1, bf, acc[1][fc], 0, 0, 0);
            }
        }
        WAIT_LGKM0;   // my LDS reads complete (frags in regs)
        SBAR;         // all waves done reading; next iter may overwrite (no vm drain)
    }

    // epilogue: bias + relu -> H (bf16) in LDS, K-padded to 128
    #pragma unroll
    for (int fc = 0; fc < 7; ++fc) {
        int c = (fc << 4) + lm;
        float bb = (c < 100) ? b1[c] : 0.0f;
        #pragma unroll
        for (int fr = 0; fr < 2; ++fr)
            #pragma unroll
            for (int r = 0; r < 4; ++r) {
                float h = acc[fr][fc][r] + bb;
                h = h > 0.0f ? h : 0.0f;
                Hl[(crow + (fr << 4) + r) * 136 + c] = bf1(h);
            }
    }
    {   // zero-fill H[:,112..127]
        u16x8 z = {0,0,0,0,0,0,0,0};
        *(u16x8*)(Hl + (tid >> 1) * 136 + 112 + ((tid & 1) << 3)) = z;
    }
    __syncthreads();

    // ---------------- GEMM2: D = sigmoid(H @ Wtheta^T + bth), K=128 ----------------
    f32x4 acc2[2][4] = {};
    const unsigned short* Wt = ws + WS_WT;
    #pragma unroll
    for (int ks = 0; ks < 4; ++ks) {
        const int k0 = (ks << 5) + lk;
        bf16x8 af0 = *(const bf16x8*)(Hl + ((wv << 5) + lm) * 136 + k0);
        bf16x8 af1 = *(const bf16x8*)(Hl + ((wv << 5) + 16 + lm) * 136 + k0);
        #pragma unroll
        for (int fc = 0; fc < 4; ++fc) {
            bf16x8 bf = *(const bf16x8*)(Wt + ((fc << 4) + lm) * 128 + k0);
            acc2[0][fc] = __builtin_amdgcn_mfma_f32_16x16x32_bf16(af0, bf, acc2[0][fc], 0, 0, 0);
            acc2[1][fc] = __builtin_amdgcn_mfma_f32_16x16x32_bf16(af1, bf, acc2[1][fc], 0, 0, 0);
        }
    }
    __syncthreads();   // done reading Hl; Dl aliases it
    #pragma unroll
    for (int fc = 0; fc < 4; ++fc) {
        int c = (fc << 4) + lm;
        float bb = (c < 63) ? bth[c] : 0.0f;
        #pragma unroll
        for (int fr = 0; fr < 2; ++fr)
            #pragma unroll
            for (int r = 0; r < 4; ++r) {
                float t = acc2[fr][fc][r] + bb;
                float d = 1.0f / (1.0f + __expf(-t));
                Dl[(crow + (fr << 4) + r) * 65 + c] = d;
            }
    }
    __syncthreads();

    // ---------------- tree products: mu (2 threads per row, 32 leaves each) ----------------
    {
        const int row = tid >> 1, p = tid & 1;
        const float* Dr = Dl + row * 65;
        float d0 = Dr[0];
        float m1 = p ? (1.0f - d0) : d0;
        float dA = Dr[1 + p];
        float m2[2]; m2[0] = m1 * dA; m2[1] = m1 * (1.0f - dA);
        float m4[4];
        #pragma unroll
        for (int i = 0; i < 2; ++i) { float d = Dr[3 + (p << 1) + i];  m4[2*i] = m2[i]*d;  m4[2*i+1] = m2[i]*(1.0f-d); }
        float m8[8];
        #pragma unroll
        for (int i = 0; i < 4; ++i) { float d = Dr[7 + (p << 2) + i];  m8[2*i] = m4[i]*d;  m8[2*i+1] = m4[i]*(1.0f-d); }
        float m16[16];
        #pragma unroll
        for (int i = 0; i < 8; ++i) { float d = Dr[15 + (p << 3) + i]; m16[2*i] = m8[i]*d; m16[2*i+1] = m8[i]*(1.0f-d); }
        float dleaf[16];
        #pragma unroll
        for (int i = 0; i < 16; ++i) dleaf[i] = Dr[31 + (p << 4) + i];
        __syncthreads();   // all reads of Dl complete; Mul may now alias it
        unsigned short* Mr = Mul + row * 72 + (p << 5);
        #pragma unroll
        for (int i = 0; i < 16; ++i) {
            float a = m16[i] * dleaf[i], b = m16[i] * (1.0f - dleaf[i]);
            *(unsigned*)(Mr + (i << 1)) = pack2(a, b);
        }
    }
    __syncthreads();

    // ---------------- GEMM3: out = mu @ pi, K=64 ----------------
    f32x4 acc3[2][7] = {};
    const unsigned short* piT = ws + WS_PI;
    #pragma unroll
    for (int ks = 0; ks < 2; ++ks) {
        const int k0 = (ks << 5) + lk;
        bf16x8 af0 = *(const bf16x8*)(Mul + ((wv << 5) + lm) * 72 + k0);
        bf16x8 af1 = *(const bf16x8*)(Mul + ((wv << 5) + 16 + lm) * 72 + k0);
        #pragma unroll
        for (int fc = 0; fc < 7; ++fc) {
            bf16x8 bf = *(const bf16x8*)(piT + ((fc << 4) + lm) * 64 + k0);
            acc3[0][fc] = __builtin_amdgcn_mfma_f32_16x16x32_bf16(af0, bf, acc3[0][fc], 0, 0, 0);
            acc3[1][fc] = __builtin_amdgcn_mfma_f32_16x16x32_bf16(af1, bf, acc3[1][fc], 0, 0, 0);
        }
    }
    #pragma unroll
    for (int fc = 0; fc < 7; ++fc) {
        int c = (fc << 4) + lm;
        if (c < 100) {
            #pragma unroll
            for (int fr = 0; fr < 2; ++fr)
                #pragma unroll
                for (int r = 0; r < 4; ++r)
                    out[(size_t)(row0 + crow + (fr << 4) + r) * 100 + c] = acc3[fr][fc][r];
        }
    }
}

extern "C" void kernel_launch(void* const* d_in, const int* in_sizes, int n_in,
                              void* d_out, int out_size, void* d_ws, size_t ws_size,
                              hipStream_t stream) {
    const float* x   = (const float*)d_in[0];
    const float* W1  = (const float*)d_in[1];
    const float* b1  = (const float*)d_in[2];
    const float* Wt  = (const float*)d_in[3];
    const float* bth = (const float*)d_in[4];
    const float* pi  = (const float*)d_in[5];
    unsigned short* ws = (unsigned short*)d_ws;

    prep_kernel<<<(PREP_TOT + 255) / 256, 256, 0, stream>>>(W1, Wt, pi, ws);
    treenet_kernel<<<NBLK, 256, 0, stream>>>(x, b1, bth, ws, (float*)d_out);
}